// Round 16
// baseline (41.529 us; speedup 1.0000x reference)
//
#include <hip/hip_runtime.h>
#include <math.h>

#define SEQ_LEN 4096
#define KSZ 128
#define OUT_LEN 3969
#define BATCH 8192
#define NB_MAIN 256      // 1 block per CU
#define NWAVES 16        // 1024 threads per block

// ---- DPP wave-64 sum, result broadcast wave-uniform via readlane 63 ----
template <int CTRL>
__device__ __forceinline__ float dpp_add(float x) {
    const int m = __builtin_amdgcn_update_dpp(0, __float_as_int(x), CTRL, 0xf, 0xf, true);
    return x + __int_as_float(m);
}
__device__ __forceinline__ float wave_sum_uniform(float x) {
    x = dpp_add<0x111>(x);   // row_shr:1
    x = dpp_add<0x112>(x);   // row_shr:2
    x = dpp_add<0x114>(x);   // row_shr:4
    x = dpp_add<0x118>(x);   // row_shr:8
    x = dpp_add<0x142>(x);   // row_bcast:15
    x = dpp_add<0x143>(x);   // row_bcast:31
    return __int_as_float(__builtin_amdgcn_readlane(__float_as_int(x), 63));
}

__device__ __forceinline__ float agent_load(const float* p) {
    return __hip_atomic_load(p, __ATOMIC_RELAXED, __HIP_MEMORY_SCOPE_AGENT);
}

// Single fused node + counter memset. Main body R10-R14 byte-identical.
// R15 RACE FIX: counters are zeroed by an 8-byte memset node each launch,
// so fetch_add returns TRUE arrival indices (0..255). The mod-residue
// trick (R13-R15) is unsound for reader-side rendezvous: with poison
// start P, "rank = old & 255" is an absolute residue, and an EARLY
// arriver can satisfy it and read unpublished slots.
// Stage 1: each block atomicExch-publishes its 256-float partial into
//   lvl1[blockIdx], bumps cnt1 (ACQ_REL). Ranks <240 exit. Ranks >=240
//   spin (tid0) until cnt1 == 256: every lvl1 slot published.
// Stage 2: chunk c = rank-240 gathers lvl1 rows 16c..16c+15 (16KB,
//   parallel on 16 CUs), publishes lvl2[c], bumps cnt2.
// Stage 3: cnt2 rank 15 (true last) gathers 16x256 in fixed order
//   (bit-deterministic, same tree as R14), dual 128-wide Hillis-Steele
//   scan, writes kernel_new (128) + bias_new (1).
__global__ __launch_bounds__(1024)
__attribute__((amdgpu_waves_per_eu(4, 4)))
void conv1d_train_fused(
    const float* __restrict__ x, const float* __restrict__ y,
    const float* __restrict__ kern, const float* __restrict__ bias,
    float* __restrict__ lvl1, float* __restrict__ lvl2,
    unsigned* __restrict__ cnt1, unsigned* __restrict__ cnt2,
    float* __restrict__ out)
{
    __shared__ float P[KSZ];          // inclusive prefix sums of kernel
    __shared__ float sl[NWAVES][256]; // combine buffer (reused by stage 2/3)
    __shared__ float colsum[256];
    __shared__ float sc[256];
    __shared__ unsigned shRank;

    const int tid  = threadIdx.x;
    const int wave = tid >> 6;
    const int lane = tid & 63;

    if (tid < KSZ) P[tid] = kern[tid];
    __syncthreads();
#pragma unroll
    for (int off = 1; off < KSZ; off <<= 1) {   // Hillis-Steele scan
        float v = 0.f;
        if (tid < KSZ) {
            v = P[tid];
            if (tid >= off) v += P[tid - off];
        }
        __syncthreads();
        if (tid < KSZ) P[tid] = v;
        __syncthreads();
    }
    const float ksum = P[KSZ - 1];
    const float bs   = bias[0];

    // Per-lane edge-correction weights (verified R2).
    float w0, w1, w2, w3;
    if (lane < 32) {
        const int j = 4 * lane;
        w0 = P[j] - ksum; w1 = P[j + 1] - ksum;
        w2 = P[j + 2] - ksum; w3 = P[j + 3] - ksum;
    } else {
        const int m = 4 * (lane - 32) - 1;
        w0 = (m >= 0) ? -P[m] : 0.f;
        w1 = -P[m + 1]; w2 = -P[m + 2]; w3 = -P[m + 3];
    }

    float g0 = 0.f, g1 = 0.f, g2 = 0.f, g3 = 0.f;
    float C0 = 0.f, db = 0.f;

    const int wg = blockIdx.x * NWAVES + wave;       // 0..4095

    for (int b = wg; b < BATCH; b += NB_MAIN * NWAVES) {   // 2 iterations
        const float4* xr = reinterpret_cast<const float4*>(x + (size_t)b * SEQ_LEN);
        float4 r[16];
#pragma unroll
        for (int i = 0; i < 16; ++i) r[i] = xr[i * 64 + lane];
        const float yv = y[b];

        float tot = 0.f;
#pragma unroll
        for (int i = 0; i < 16; ++i) tot += (r[i].x + r[i].y) + (r[i].z + r[i].w);

        const float4 e = (lane < 32) ? r[0] : r[15];
        const float corr = ((w0 * e.x + w1 * e.y) + (w2 * e.z + w3 * e.w));

        const float t = wave_sum_uniform(tot);
        const float c = wave_sum_uniform(corr);

        const float logits = (ksum * t + c) * (1.f / (float)OUT_LEN) + bs;
        const float sig    = 1.f / (1.f + expf(-logits));
        const float dconv  = (sig - yv) * (1.f / (float)OUT_LEN);

        g0 += dconv * e.x; g1 += dconv * e.y;
        g2 += dconv * e.z; g3 += dconv * e.w;
        C0 += dconv * t;   db += dconv;
    }

    // Per-wave writeout to LDS: [0..126]=G, [127]=C0, [128..254]=H, [255]=db
    if (lane < 32) {
        const int j = 4 * lane;
        sl[wave][j]     = g0;
        sl[wave][j + 1] = g1;
        sl[wave][j + 2] = g2;
        if (j + 3 < 127) sl[wave][j + 3] = g3;
    } else {
        const int s0 = 4 * lane - 1;
        if (lane > 32) sl[wave][s0] = g0;
        sl[wave][s0 + 1] = g1;
        sl[wave][s0 + 2] = g2;
        sl[wave][s0 + 3] = g3;
    }
    if (lane == 0) { sl[wave][127] = C0; sl[wave][255] = db; }
    __syncthreads();

    // ---- Stage 1: publish block partial (atomic RMW = coherence point) ----
    if (tid < 256) {
        float s = 0.f;
#pragma unroll
        for (int w = 0; w < NWAVES; ++w) s += sl[w][tid];
        atomicExch(&lvl1[(size_t)blockIdx.x * 256 + tid], s);
    }
    __syncthreads();             // all exchanges in this block retired

    if (tid == 0) {
        const unsigned rank = __hip_atomic_fetch_add(
            cnt1, 1u, __ATOMIC_ACQ_REL, __HIP_MEMORY_SCOPE_AGENT);
        shRank = rank;           // TRUE arrival index (counter memset to 0)
        if (rank >= (unsigned)(NB_MAIN - 16)) {
            while (__hip_atomic_load(cnt1, __ATOMIC_ACQUIRE,
                                     __HIP_MEMORY_SCOPE_AGENT)
                   < (unsigned)NB_MAIN) {}
        }
    }
    __syncthreads();
    const unsigned rank1 = shRank;
    if (rank1 < (unsigned)(NB_MAIN - 16)) return;

    // ---- Stage 2: 16 blocks, chunk c gathers lvl1 rows 16c..16c+15 ----
    const int c = (int)(rank1 - (unsigned)(NB_MAIN - 16));
    {
        const int rsub = tid >> 6;               // 0..15
        const int f4c  = tid & 63;
        const float* rowp = lvl1 + (size_t)(16 * c + rsub) * 256 + 4 * f4c;
        sl[rsub][4 * f4c + 0] = agent_load(rowp + 0);
        sl[rsub][4 * f4c + 1] = agent_load(rowp + 1);
        sl[rsub][4 * f4c + 2] = agent_load(rowp + 2);
        sl[rsub][4 * f4c + 3] = agent_load(rowp + 3);
    }
    __syncthreads();
    if (tid < 256) {
        float s = 0.f;
#pragma unroll
        for (int w = 0; w < NWAVES; ++w) s += sl[w][tid];
        atomicExch(&lvl2[(size_t)c * 256 + tid], s);
    }
    __syncthreads();             // drain exchanges
    if (tid == 0) {
        const unsigned old2 = __hip_atomic_fetch_add(
            cnt2, 1u, __ATOMIC_ACQ_REL, __HIP_MEMORY_SCOPE_AGENT);
        shRank = old2;           // true arrival index 0..15
    }
    __syncthreads();
    if (shRank != 15u) return;   // true last arriver finalizes

    // ---- Stage 3: final gather (fixed order), scan, output ----
    {
        const int w4 = tid >> 8;                 // 0..3
        const int cc = tid & 255;
        float s = 0.f;
#pragma unroll
        for (int w = 0; w < 4; ++w)
            s += agent_load(&lvl2[(size_t)(w4 + 4 * w) * 256 + cc]);
        sl[w4][cc] = s;
    }
    __syncthreads();
    if (tid < 256)
        colsum[tid] = (sl[0][tid] + sl[1][tid]) + (sl[2][tid] + sl[3][tid]);
    __syncthreads();

    // pre/suf via two simultaneous 128-wide Hillis-Steele inclusive scans.
    float gh = 0.f;
    if (tid < 256) {
        gh = colsum[tid];
        if (tid == 127 || tid == 255) gh = 0.f;
        sc[tid] = gh;
    }
    __syncthreads();
#pragma unroll
    for (int off = 1; off < 128; off <<= 1) {
        float add = 0.f;
        if (tid < 256 && (tid & 127) >= off) add = sc[tid - off];
        __syncthreads();
        if (tid < 256) sc[tid] += add;
        __syncthreads();
    }

    if (tid < 128) {
        const float C0a  = colsum[127];
        const float TH   = sc[255];
        const float pre  = sc[tid] - gh;
        const float inch = sc[128 + tid];
        const float h_t  = (tid < 127) ? colsum[128 + tid] : 0.f;
        const float suf  = TH - (inch - h_t);
        const float dk = (C0a - pre - suf) * (1.f / (float)BATCH);
        out[tid] = kern[tid] - dk;
    }
    if (tid == 0) {
        const float dbo = colsum[255] * ((float)OUT_LEN / (float)BATCH);
        out[128] = bias[0] - dbo;
    }
}

extern "C" void kernel_launch(void* const* d_in, const int* in_sizes, int n_in,
                              void* d_out, int out_size, void* d_ws, size_t ws_size,
                              hipStream_t stream) {
    (void)in_sizes; (void)n_in; (void)out_size; (void)ws_size;
    const float* x    = (const float*)d_in[0];
    const float* y    = (const float*)d_in[1];
    const float* kern = (const float*)d_in[2];
    const float* bias = (const float*)d_in[3];
    float* out = (float*)d_out;

    // ws layout: lvl1[256*256] floats, lvl2[16*256] floats, cnt1, cnt2.
    // lvl slots are overwrite-published (atomicExch) -> poison-immune.
    // Counters MUST be zeroed each launch (true arrival ranks): 8-byte
    // memset node, graph-capturable.
    float*    lvl1 = (float*)d_ws;
    float*    lvl2 = lvl1 + (size_t)NB_MAIN * 256;
    unsigned* cnt1 = (unsigned*)(lvl2 + (size_t)16 * 256);
    unsigned* cnt2 = cnt1 + 1;

    hipMemsetAsync(cnt1, 0, 2 * sizeof(unsigned), stream);
    hipLaunchKernelGGL(conv1d_train_fused, dim3(NB_MAIN), dim3(1024), 0, stream,
                       x, y, kern, bias, lvl1, lvl2, cnt1, cnt2, out);
}

// Round 17
// 35.988 us; speedup vs baseline: 1.1540x; 1.1540x over previous
//
#include <hip/hip_runtime.h>
#include <math.h>

#define SEQ_LEN 4096
#define KSZ 128
#define OUT_LEN 3969
#define BATCH 8192
#define NB_MAIN 256      // main grid: 1 block per CU
#define NWAVES 16        // 1024 threads per block
#define TAIL_NB 16       // tail blocks (one accum slot each)

// ---- DPP wave-64 sum, result broadcast wave-uniform via readlane 63 ----
// (A/B verified R6 vs R8: ~2us faster than shfl_xor butterfly.)
template <int CTRL>
__device__ __forceinline__ float dpp_add(float x) {
    const int m = __builtin_amdgcn_update_dpp(0, __float_as_int(x), CTRL, 0xf, 0xf, true);
    return x + __int_as_float(m);
}
__device__ __forceinline__ float wave_sum_uniform(float x) {
    x = dpp_add<0x111>(x);   // row_shr:1
    x = dpp_add<0x112>(x);   // row_shr:2
    x = dpp_add<0x114>(x);   // row_shr:4
    x = dpp_add<0x118>(x);   // row_shr:8
    x = dpp_add<0x142>(x);   // row_bcast:15
    x = dpp_add<0x143>(x);   // row_bcast:31
    return __int_as_float(__builtin_amdgcn_readlane(__float_as_int(x), 63));
}

// Main pass (R10-R14, byte-identical; measured 22.4us incl node =
// 5.95 TB/s, ~94% of achievable): 256 blocks x 1024 threads, 16 waves/CU.
// One wave = one row, 2 rows/wave, no barriers in the row loop, 16 float4
// loads in flight, DPP reduce, edge gradients in registers.
__global__ __launch_bounds__(1024)
__attribute__((amdgpu_waves_per_eu(4, 4)))
void conv1d_train_main(
    const float* __restrict__ x, const float* __restrict__ y,
    const float* __restrict__ kern, const float* __restrict__ bias,
    float* __restrict__ partial)
{
    __shared__ float P[KSZ];          // inclusive prefix sums of kernel
    __shared__ float sl[NWAVES][256]; // per-wave partials for block combine

    const int tid  = threadIdx.x;
    const int wave = tid >> 6;
    const int lane = tid & 63;

    if (tid < KSZ) P[tid] = kern[tid];
    __syncthreads();
#pragma unroll
    for (int off = 1; off < KSZ; off <<= 1) {   // Hillis-Steele scan
        float v = 0.f;
        if (tid < KSZ) {
            v = P[tid];
            if (tid >= off) v += P[tid - off];
        }
        __syncthreads();
        if (tid < KSZ) P[tid] = v;
        __syncthreads();
    }
    const float ksum = P[KSZ - 1];
    const float bs   = bias[0];

    // Per-lane edge-correction weights (verified R2).
    float w0, w1, w2, w3;
    if (lane < 32) {
        const int j = 4 * lane;
        w0 = P[j] - ksum; w1 = P[j + 1] - ksum;
        w2 = P[j + 2] - ksum; w3 = P[j + 3] - ksum;
    } else {
        const int m = 4 * (lane - 32) - 1;
        w0 = (m >= 0) ? -P[m] : 0.f;
        w1 = -P[m + 1]; w2 = -P[m + 2]; w3 = -P[m + 3];
    }

    float g0 = 0.f, g1 = 0.f, g2 = 0.f, g3 = 0.f;  // dconv-weighted edge accum
    float C0 = 0.f, db = 0.f;

    const int wg = blockIdx.x * NWAVES + wave;       // 0..4095

    for (int b = wg; b < BATCH; b += NB_MAIN * NWAVES) {   // 2 iterations
        const float4* xr = reinterpret_cast<const float4*>(x + (size_t)b * SEQ_LEN);
        float4 r[16];
#pragma unroll
        for (int i = 0; i < 16; ++i) r[i] = xr[i * 64 + lane];
        const float yv = y[b];                       // broadcast load

        float tot = 0.f;
#pragma unroll
        for (int i = 0; i < 16; ++i) tot += (r[i].x + r[i].y) + (r[i].z + r[i].w);

        const float4 e = (lane < 32) ? r[0] : r[15];
        const float corr = ((w0 * e.x + w1 * e.y) + (w2 * e.z + w3 * e.w));

        const float t = wave_sum_uniform(tot);       // wave-uniform scalars
        const float c = wave_sum_uniform(corr);

        const float logits = (ksum * t + c) * (1.f / (float)OUT_LEN) + bs;
        const float sig    = 1.f / (1.f + expf(-logits));
        const float dconv  = (sig - yv) * (1.f / (float)OUT_LEN);

        g0 += dconv * e.x; g1 += dconv * e.y;
        g2 += dconv * e.z; g3 += dconv * e.w;
        C0 += dconv * t;   db += dconv;
    }

    // Per-wave writeout to LDS: [0..126]=G, [127]=C0, [128..254]=H, [255]=db
    if (lane < 32) {
        const int j = 4 * lane;
        sl[wave][j]     = g0;
        sl[wave][j + 1] = g1;
        sl[wave][j + 2] = g2;
        if (j + 3 < 127) sl[wave][j + 3] = g3;   // skip unused G[127]
    } else {
        const int s0 = 4 * lane - 1;             // slot = 128 + m
        if (lane > 32) sl[wave][s0] = g0;        // lane 32 q=0 -> m=-1, skip
        sl[wave][s0 + 1] = g1;
        sl[wave][s0 + 2] = g2;
        sl[wave][s0 + 3] = g3;                   // lane 63 -> slot 254
    }
    if (lane == 0) { sl[wave][127] = C0; sl[wave][255] = db; }
    __syncthreads();
    if (tid < 256) {
        float s = 0.f;
#pragma unroll
        for (int w = 0; w < NWAVES; ++w) s += sl[w][tid];
        partial[(size_t)blockIdx.x * 256 + tid] = s;   // coalesced 1KB/block
    }
}

// Tail (R14 structure; R15 race lesson applied): counter is ZEROED by a
// memset node each launch, so fetch_add returns TRUE arrival indices and
// "old == 15" really is the last arriver (the R13/R14 mod-residue test
// was unsound under counter poison — an early arriver could match the
// residue and read unpublished slots).
// 16 blocks x 1024 threads; block b reduces rows 16b..16b+15 of partial
// (one float4/thread), publishes via atomicExch (coherence-point RMW, no
// fence needed, poison-immune, no contention). Last arriver gathers with
// all 1024 threads (4 atomic loads each, fixed order -> bit-deterministic),
// computes pre/suf via two 128-wide Hillis-Steele scans, writes
// kernel_new (128) + bias_new (1).
__global__ __launch_bounds__(1024) void conv1d_train_tail(
    const float* __restrict__ partial, float* __restrict__ accum,
    unsigned* __restrict__ counter,
    const float* __restrict__ kern, const float* __restrict__ bias,
    float* __restrict__ out)
{
    __shared__ float slr[NWAVES][256];
    __shared__ float colsum[256];
    __shared__ float sc[256];
    __shared__ unsigned lastFlag;

    const int tid   = threadIdx.x;
    const int rsub  = tid >> 6;                 // 0..15 (row within block's 16)
    const int f4c   = tid & 63;                 // float4 column
    const int rbase = blockIdx.x * 16;

    // Phase A: one float4 per thread covers this block's 16 rows.
    const float4* p4 = reinterpret_cast<const float4*>(partial);
    const float4 v = p4[(size_t)(rbase + rsub) * 64 + f4c];
    slr[rsub][4 * f4c + 0] = v.x;
    slr[rsub][4 * f4c + 1] = v.y;
    slr[rsub][4 * f4c + 2] = v.z;
    slr[rsub][4 * f4c + 3] = v.w;
    __syncthreads();

    if (tid < 256) {
        float s = 0.f;
#pragma unroll
        for (int w = 0; w < NWAVES; ++w) s += slr[w][tid];
        atomicExch(&accum[(size_t)blockIdx.x * 256 + tid], s);  // publish
    }
    __syncthreads();            // exchanges retired

    if (tid == 0) {
        const unsigned old = __hip_atomic_fetch_add(
            counter, 1u, __ATOMIC_ACQ_REL, __HIP_MEMORY_SCOPE_AGENT);
        lastFlag = (old == (unsigned)(TAIL_NB - 1)) ? 1u : 0u;  // true last
    }
    __syncthreads();
    if (!lastFlag) return;

    // Last block: gather with all 1024 threads (4 slots each, fixed order).
    {
        const int w4 = tid >> 8;                // 0..3
        const int c  = tid & 255;
        float s = 0.f;
#pragma unroll
        for (int w = 0; w < 4; ++w)
            s += __hip_atomic_load(&accum[(size_t)(w4 + 4 * w) * 256 + c],
                                   __ATOMIC_RELAXED, __HIP_MEMORY_SCOPE_AGENT);
        slr[w4][c] = s;
    }
    __syncthreads();
    if (tid < 256)
        colsum[tid] = (slr[0][tid] + slr[1][tid]) + (slr[2][tid] + slr[3][tid]);
    __syncthreads();

    // pre/suf via two simultaneous 128-wide Hillis-Steele inclusive scans:
    // lower half scans g = colsum[0..126] (127 slot = C0 -> 0),
    // upper half scans h = colsum[128..254] (255 slot = db -> 0).
    float gh = 0.f;
    if (tid < 256) {
        gh = colsum[tid];
        if (tid == 127 || tid == 255) gh = 0.f;
        sc[tid] = gh;
    }
    __syncthreads();
#pragma unroll
    for (int off = 1; off < 128; off <<= 1) {
        float add = 0.f;
        if (tid < 256 && (tid & 127) >= off) add = sc[tid - off];
        __syncthreads();
        if (tid < 256) sc[tid] += add;
        __syncthreads();
    }

    if (tid < 128) {
        const float C0   = colsum[127];
        const float TH   = sc[255];              // sum of all h
        const float pre  = sc[tid] - gh;         // exclusive prefix of g
        const float inch = sc[128 + tid];
        const float h_t  = (tid < 127) ? colsum[128 + tid] : 0.f;
        const float suf  = TH - (inch - h_t);    // sum h[j], j >= tid
        const float dk = (C0 - pre - suf) * (1.f / (float)BATCH);
        out[tid] = kern[tid] - dk;
    }
    if (tid == 0) {
        const float dbo = colsum[255] * ((float)OUT_LEN / (float)BATCH);
        out[128] = bias[0] - dbo;
    }
}

extern "C" void kernel_launch(void* const* d_in, const int* in_sizes, int n_in,
                              void* d_out, int out_size, void* d_ws, size_t ws_size,
                              hipStream_t stream) {
    (void)in_sizes; (void)n_in; (void)out_size; (void)ws_size;
    const float* x    = (const float*)d_in[0];
    const float* y    = (const float*)d_in[1];
    const float* kern = (const float*)d_in[2];
    const float* bias = (const float*)d_in[3];
    float* out = (float*)d_out;

    // ws layout: partial[256*256] floats (256KB), accum[16*256] floats
    // (16KB), counter (4B). partial/accum fully overwritten every launch;
    // counter zeroed by the memset node (true arrival ranks — sound).
    float*    partial = (float*)d_ws;
    float*    accum   = partial + (size_t)NB_MAIN * 256;
    unsigned* counter = (unsigned*)(accum + (size_t)TAIL_NB * 256);

    hipMemsetAsync(counter, 0, sizeof(unsigned), stream);
    hipLaunchKernelGGL(conv1d_train_main, dim3(NB_MAIN), dim3(1024), 0, stream,
                       x, y, kern, bias, partial);
    hipLaunchKernelGGL(conv1d_train_tail, dim3(TAIL_NB), dim3(1024), 0, stream,
                       partial, accum, counter, kern, bias, out);
}

// Round 18
// 31.312 us; speedup vs baseline: 1.3263x; 1.1493x over previous
//
#include <hip/hip_runtime.h>
#include <math.h>

#define SEQ_LEN 4096
#define KSZ 128
#define OUT_LEN 3969
#define BATCH 8192
#define NB_MAIN 256      // main grid: 1 block per CU
#define NWAVES 16        // 1024 threads per block
#define TAIL_NB 16       // tail blocks (one accum slot each)

// ---- DPP wave-64 sum, result broadcast wave-uniform via readlane 63 ----
// (A/B verified R6 vs R8: ~2us faster than shfl_xor butterfly.)
template <int CTRL>
__device__ __forceinline__ float dpp_add(float x) {
    const int m = __builtin_amdgcn_update_dpp(0, __float_as_int(x), CTRL, 0xf, 0xf, true);
    return x + __int_as_float(m);
}
__device__ __forceinline__ float wave_sum_uniform(float x) {
    x = dpp_add<0x111>(x);   // row_shr:1
    x = dpp_add<0x112>(x);   // row_shr:2
    x = dpp_add<0x114>(x);   // row_shr:4
    x = dpp_add<0x118>(x);   // row_shr:8
    x = dpp_add<0x142>(x);   // row_bcast:15
    x = dpp_add<0x143>(x);   // row_bcast:31
    return __int_as_float(__builtin_amdgcn_readlane(__float_as_int(x), 63));
}

// Main pass (R10-R14 loop, byte-identical; measured 22.4us incl node =
// 5.95 TB/s, ~94% of achievable). ONE addition vs R14: block 0 zeroes the
// tail's counter (atomic store; the AQL dispatch barrier publishes it to
// the tail) — this gives R17's sound true-arrival ranks WITHOUT R17's
// ~4.7us memset node.
__global__ __launch_bounds__(1024)
__attribute__((amdgpu_waves_per_eu(4, 4)))
void conv1d_train_main(
    const float* __restrict__ x, const float* __restrict__ y,
    const float* __restrict__ kern, const float* __restrict__ bias,
    float* __restrict__ partial, unsigned* __restrict__ counter)
{
    __shared__ float P[KSZ];          // inclusive prefix sums of kernel
    __shared__ float sl[NWAVES][256]; // per-wave partials for block combine

    const int tid  = threadIdx.x;
    const int wave = tid >> 6;
    const int lane = tid & 63;

    if (blockIdx.x == 0 && tid == 0)  // reset tail counter for this launch
        __hip_atomic_store(counter, 0u, __ATOMIC_RELAXED,
                           __HIP_MEMORY_SCOPE_AGENT);

    if (tid < KSZ) P[tid] = kern[tid];
    __syncthreads();
#pragma unroll
    for (int off = 1; off < KSZ; off <<= 1) {   // Hillis-Steele scan
        float v = 0.f;
        if (tid < KSZ) {
            v = P[tid];
            if (tid >= off) v += P[tid - off];
        }
        __syncthreads();
        if (tid < KSZ) P[tid] = v;
        __syncthreads();
    }
    const float ksum = P[KSZ - 1];
    const float bs   = bias[0];

    // Per-lane edge-correction weights (verified R2).
    float w0, w1, w2, w3;
    if (lane < 32) {
        const int j = 4 * lane;
        w0 = P[j] - ksum; w1 = P[j + 1] - ksum;
        w2 = P[j + 2] - ksum; w3 = P[j + 3] - ksum;
    } else {
        const int m = 4 * (lane - 32) - 1;
        w0 = (m >= 0) ? -P[m] : 0.f;
        w1 = -P[m + 1]; w2 = -P[m + 2]; w3 = -P[m + 3];
    }

    float g0 = 0.f, g1 = 0.f, g2 = 0.f, g3 = 0.f;  // dconv-weighted edge accum
    float C0 = 0.f, db = 0.f;

    const int wg = blockIdx.x * NWAVES + wave;       // 0..4095

    for (int b = wg; b < BATCH; b += NB_MAIN * NWAVES) {   // 2 iterations
        const float4* xr = reinterpret_cast<const float4*>(x + (size_t)b * SEQ_LEN);
        float4 r[16];
#pragma unroll
        for (int i = 0; i < 16; ++i) r[i] = xr[i * 64 + lane];
        const float yv = y[b];                       // broadcast load

        float tot = 0.f;
#pragma unroll
        for (int i = 0; i < 16; ++i) tot += (r[i].x + r[i].y) + (r[i].z + r[i].w);

        const float4 e = (lane < 32) ? r[0] : r[15];
        const float corr = ((w0 * e.x + w1 * e.y) + (w2 * e.z + w3 * e.w));

        const float t = wave_sum_uniform(tot);       // wave-uniform scalars
        const float c = wave_sum_uniform(corr);

        const float logits = (ksum * t + c) * (1.f / (float)OUT_LEN) + bs;
        const float sig    = 1.f / (1.f + expf(-logits));
        const float dconv  = (sig - yv) * (1.f / (float)OUT_LEN);

        g0 += dconv * e.x; g1 += dconv * e.y;
        g2 += dconv * e.z; g3 += dconv * e.w;
        C0 += dconv * t;   db += dconv;
    }

    // Per-wave writeout to LDS: [0..126]=G, [127]=C0, [128..254]=H, [255]=db
    if (lane < 32) {
        const int j = 4 * lane;
        sl[wave][j]     = g0;
        sl[wave][j + 1] = g1;
        sl[wave][j + 2] = g2;
        if (j + 3 < 127) sl[wave][j + 3] = g3;   // skip unused G[127]
    } else {
        const int s0 = 4 * lane - 1;             // slot = 128 + m
        if (lane > 32) sl[wave][s0] = g0;        // lane 32 q=0 -> m=-1, skip
        sl[wave][s0 + 1] = g1;
        sl[wave][s0 + 2] = g2;
        sl[wave][s0 + 3] = g3;                   // lane 63 -> slot 254
    }
    if (lane == 0) { sl[wave][127] = C0; sl[wave][255] = db; }
    __syncthreads();
    if (tid < 256) {
        float s = 0.f;
#pragma unroll
        for (int w = 0; w < NWAVES; ++w) s += sl[w][tid];
        partial[(size_t)blockIdx.x * 256 + tid] = s;   // coalesced 1KB/block
    }
}

// Tail (R17, byte-identical): counter was zeroed by main (previous
// dispatch, AQL barrier guarantees visibility), so fetch_add returns TRUE
// arrival indices and "old == 15" is genuinely the last arriver — sound
// under workspace poison, unlike the R13/R14 mod-residue test.
// 16 blocks x 1024 threads; block b reduces rows 16b..16b+15 of partial
// (one float4/thread), publishes via atomicExch (coherence-point RMW, no
// fence needed, poison-immune). Last arriver gathers with all 1024
// threads (fixed order -> bit-deterministic), dual 128-wide Hillis-Steele
// scans for pre/suf, writes kernel_new (128) + bias_new (1).
__global__ __launch_bounds__(1024) void conv1d_train_tail(
    const float* __restrict__ partial, float* __restrict__ accum,
    unsigned* __restrict__ counter,
    const float* __restrict__ kern, const float* __restrict__ bias,
    float* __restrict__ out)
{
    __shared__ float slr[NWAVES][256];
    __shared__ float colsum[256];
    __shared__ float sc[256];
    __shared__ unsigned lastFlag;

    const int tid   = threadIdx.x;
    const int rsub  = tid >> 6;                 // 0..15 (row within block's 16)
    const int f4c   = tid & 63;                 // float4 column
    const int rbase = blockIdx.x * 16;

    // Phase A: one float4 per thread covers this block's 16 rows.
    const float4* p4 = reinterpret_cast<const float4*>(partial);
    const float4 v = p4[(size_t)(rbase + rsub) * 64 + f4c];
    slr[rsub][4 * f4c + 0] = v.x;
    slr[rsub][4 * f4c + 1] = v.y;
    slr[rsub][4 * f4c + 2] = v.z;
    slr[rsub][4 * f4c + 3] = v.w;
    __syncthreads();

    if (tid < 256) {
        float s = 0.f;
#pragma unroll
        for (int w = 0; w < NWAVES; ++w) s += slr[w][tid];
        atomicExch(&accum[(size_t)blockIdx.x * 256 + tid], s);  // publish
    }
    __syncthreads();            // exchanges retired

    if (tid == 0) {
        const unsigned old = __hip_atomic_fetch_add(
            counter, 1u, __ATOMIC_ACQ_REL, __HIP_MEMORY_SCOPE_AGENT);
        lastFlag = (old == (unsigned)(TAIL_NB - 1)) ? 1u : 0u;  // true last
    }
    __syncthreads();
    if (!lastFlag) return;

    // Last block: gather with all 1024 threads (4 slots each, fixed order).
    {
        const int w4 = tid >> 8;                // 0..3
        const int c  = tid & 255;
        float s = 0.f;
#pragma unroll
        for (int w = 0; w < 4; ++w)
            s += __hip_atomic_load(&accum[(size_t)(w4 + 4 * w) * 256 + c],
                                   __ATOMIC_RELAXED, __HIP_MEMORY_SCOPE_AGENT);
        slr[w4][c] = s;
    }
    __syncthreads();
    if (tid < 256)
        colsum[tid] = (slr[0][tid] + slr[1][tid]) + (slr[2][tid] + slr[3][tid]);
    __syncthreads();

    // pre/suf via two simultaneous 128-wide Hillis-Steele inclusive scans:
    // lower half scans g = colsum[0..126] (127 slot = C0 -> 0),
    // upper half scans h = colsum[128..254] (255 slot = db -> 0).
    float gh = 0.f;
    if (tid < 256) {
        gh = colsum[tid];
        if (tid == 127 || tid == 255) gh = 0.f;
        sc[tid] = gh;
    }
    __syncthreads();
#pragma unroll
    for (int off = 1; off < 128; off <<= 1) {
        float add = 0.f;
        if (tid < 256 && (tid & 127) >= off) add = sc[tid - off];
        __syncthreads();
        if (tid < 256) sc[tid] += add;
        __syncthreads();
    }

    if (tid < 128) {
        const float C0   = colsum[127];
        const float TH   = sc[255];              // sum of all h
        const float pre  = sc[tid] - gh;         // exclusive prefix of g
        const float inch = sc[128 + tid];
        const float h_t  = (tid < 127) ? colsum[128 + tid] : 0.f;
        const float suf  = TH - (inch - h_t);    // sum h[j], j >= tid
        const float dk = (C0 - pre - suf) * (1.f / (float)BATCH);
        out[tid] = kern[tid] - dk;
    }
    if (tid == 0) {
        const float dbo = colsum[255] * ((float)OUT_LEN / (float)BATCH);
        out[128] = bias[0] - dbo;
    }
}

extern "C" void kernel_launch(void* const* d_in, const int* in_sizes, int n_in,
                              void* d_out, int out_size, void* d_ws, size_t ws_size,
                              hipStream_t stream) {
    (void)in_sizes; (void)n_in; (void)out_size; (void)ws_size;
    const float* x    = (const float*)d_in[0];
    const float* y    = (const float*)d_in[1];
    const float* kern = (const float*)d_in[2];
    const float* bias = (const float*)d_in[3];
    float* out = (float*)d_out;

    // ws layout: partial[256*256] floats (256KB), accum[16*256] floats
    // (16KB), counter (4B). partial/accum fully overwritten every launch;
    // counter zeroed BY THE MAIN KERNEL (AQL barrier publishes it to the
    // tail) — no memset node needed.
    float*    partial = (float*)d_ws;
    float*    accum   = partial + (size_t)NB_MAIN * 256;
    unsigned* counter = (unsigned*)(accum + (size_t)TAIL_NB * 256);

    hipLaunchKernelGGL(conv1d_train_main, dim3(NB_MAIN), dim3(1024), 0, stream,
                       x, y, kern, bias, partial, counter);
    hipLaunchKernelGGL(conv1d_train_tail, dim3(TAIL_NB), dim3(1024), 0, stream,
                       partial, accum, counter, kern, bias, out);
}